// Round 10
// baseline (427.883 us; speedup 1.0000x reference)
//
#include <hip/hip_runtime.h>
#include <hip/hip_bf16.h>
#include <math.h>

// Problem constants
#define TT 243
#define CC 544            // J*IC
#define NBB 81            // T/BS
#define KK 6
#define HH 8
#define HD 68             // C/H
#define DEPTH 2
#define HID 1088          // 2*C
#define BB 512
#define MTOK 3072         // B*K tokens
#define EPSF 1e-6f
#define NPART 10          // stats partials per row: 5 col-tiles x 2 waves (N=544)

typedef __attribute__((ext_vector_type(8))) short bf16x8;
typedef __attribute__((ext_vector_type(4))) float f32x4;

__device__ __forceinline__ __hip_bfloat16 f2b(float f) { return __float2bfloat16(f); }
__device__ __forceinline__ unsigned short f2bu(float f) {
    __hip_bfloat16 h = __float2bfloat16(f);
    return *(unsigned short*)&h;
}
__device__ __forceinline__ float b2f_lo(unsigned int u) { return __uint_as_float(u << 16); }
__device__ __forceinline__ float b2f_hi(unsigned int u) { return __uint_as_float(u & 0xffff0000u); }

__device__ __forceinline__ ushort4 norm4(float4 f, float m, float inv,
                                         const float* sg, const float* sb, int c) {
    ushort4 o;
    o.x = f2bu((f.x - m) * inv * sg[c + 0] + sb[c + 0]);
    o.y = f2bu((f.y - m) * inv * sg[c + 1] + sb[c + 1]);
    o.z = f2bu((f.z - m) * inv * sg[c + 2] + sb[c + 2]);
    o.w = f2bu((f.w - m) * inv * sg[c + 3] + sb[c + 3]);
    return o;
}

// weight conversion segment ends (float4-index space): qkv | proj | mfc1 | mfc2
#define E0 443904
#define E1 591872
#define E2 887808
#define E3 1183744

// bw_kernel block ranges
#define RS_BLOCKS 3888
#define PS_BLOCKS 8
#define WC_BLOCKS 4624
#define BW_GRID (RS_BLOCKS + PS_BLOCKS + WC_BLOCKS)

// ---------------------------------------------------------------------------
// bw_kernel: pure-bandwidth pass (proven R5 version, unchanged)
// ---------------------------------------------------------------------------
__global__ __launch_bounds__(256, 4) void bw_kernel(
    const float* __restrict__ x, const float* __restrict__ pos,
    const float* __restrict__ qkvw, const float* __restrict__ projw,
    const float* __restrict__ mfc1w, const float* __restrict__ mfc2w,
    unsigned short* __restrict__ wbf,
    float* __restrict__ L, float* __restrict__ R, float* __restrict__ pLR)
{
    const int blk = blockIdx.x;
    const int tid = threadIdx.x;

    if (blk < RS_BLOCKS) {
        const int w = tid >> 6;
        const int lane = tid & 63;
        const int oct = lane & 7;
        const int rsub = lane >> 3;
        const int r = (blk * 4 + w) * 8 + rsub;
        const float4* xr = (const float4*)x + (size_t)r * 136;
        float4 xs[17];
#pragma unroll
        for (int j = 0; j < 17; ++j) xs[j] = xr[oct + j * 8];
        float aL = 0.0f, aR = 0.0f;
#pragma unroll
        for (int j = 0; j < 17; ++j) {
            const float s = (xs[j].x + xs[j].y) + (xs[j].z + xs[j].w);
            if (j < 8) aL += s;
            else if (j == 8) { if (oct < 4) aL += s; else aR += s; }
            else aR += s;
        }
#pragma unroll
        for (int m = 1; m < 8; m <<= 1) {
            aL += __shfl_xor(aL, m);
            aR += __shfl_xor(aR, m);
        }
        if (oct == 0) { L[r] = aL; R[r] = aR; }
        return;
    }

    if (blk < RS_BLOCKS + PS_BLOCKS) {
        const int w = tid >> 6;
        const int lane = tid & 63;
        const int oct = lane & 7;
        const int rsub = lane >> 3;
        const int r = (blk - RS_BLOCKS) * 32 + w * 8 + rsub;
        const int rc = (r < TT) ? r : (TT - 1);
        const float4* pr = (const float4*)pos + (size_t)rc * 136;
        float4 xs[17];
#pragma unroll
        for (int j = 0; j < 17; ++j) xs[j] = pr[oct + j * 8];
        float aL = 0.0f, aR = 0.0f;
#pragma unroll
        for (int j = 0; j < 17; ++j) {
            const float s = (xs[j].x + xs[j].y) + (xs[j].z + xs[j].w);
            if (j < 8) aL += s;
            else if (j == 8) { if (oct < 4) aL += s; else aR += s; }
            else aR += s;
        }
#pragma unroll
        for (int m = 1; m < 8; m <<= 1) {
            aL += __shfl_xor(aL, m);
            aR += __shfl_xor(aR, m);
        }
        if (oct == 0 && r < TT) { pLR[r] = aL; pLR[TT + r] = aR; }
        return;
    }

    const int i = (blk - RS_BLOCKS - PS_BLOCKS) * 256 + tid;
    if (i < E3) {
        float4 v;
        if (i < E0)      v = ((const float4*)qkvw)[i];
        else if (i < E1) v = ((const float4*)projw)[i - E0];
        else if (i < E2) v = ((const float4*)mfc1w)[i - E1];
        else             v = ((const float4*)mfc2w)[i - E2];
        ushort4 o;
        o.x = f2bu(v.x); o.y = f2bu(v.y); o.z = f2bu(v.z); o.w = f2bu(v.w);
        ((ushort4*)wbf)[i] = o;
    }
}

// ---------------------------------------------------------------------------
// select: y0, MLP, top-6, gather + fused ln1_0 -> hb (R5, unchanged)
// ---------------------------------------------------------------------------
__global__ __launch_bounds__(128) void select_kernel(
    const float* __restrict__ L, const float* __restrict__ R,
    const float* __restrict__ pLR,
    const float* __restrict__ fc1, const float* __restrict__ fc2,
    const float* __restrict__ x, const float* __restrict__ pos,
    const float* __restrict__ ln1g, const float* __restrict__ ln1b,
    float* __restrict__ t, unsigned short* __restrict__ hb)
{
    const int b = blockIdx.x;
    const int tid = threadIdx.x;
    __shared__ float sf1[NBB * NBB];
    __shared__ float sf2[NBB * NBB];
    __shared__ float sy[NBB], sz[NBB], swv[NBB];
    __shared__ int sidx[KK];
    __shared__ __align__(16) float st[KK][CC];

    const int w = tid >> 6;
    const int lane = tid & 63;
    const float4* x4 = (const float4*)x;
    const float4* p4 = (const float4*)pos;

    for (int i = tid; i < NBB * NBB; i += 128) {
        sf1[i] = fc1[i];
        sf2[i] = fc2[i];
    }

    if (tid < NBB) {
        const int n = tid;
        const float* Lb = L + (size_t)b * TT;
        const float* Rb = R + (size_t)b * TT;
        const float* pL = pLR;
        const float* pR = pLR + TT;
        float s = Lb[3 * n] + Lb[3 * n + 1] + Rb[3 * n] + Rb[3 * n + 1] + Rb[3 * n + 2]
                + pL[3 * n] + pL[3 * n + 1] + pR[3 * n] + pR[3 * n + 1] + pR[3 * n + 2];
        if (n > 0) s += Lb[3 * n - 1] + pL[3 * n - 1];
        sy[n] = s * (1.0f / (3.0f * (float)CC));
    }
    __syncthreads();
    if (tid < NBB) {
        float s = 0.0f;
        for (int j = 0; j < NBB; ++j) s += sf1[tid * NBB + j] * sy[j];
        sz[tid] = fmaxf(s, 0.0f);
    }
    __syncthreads();
    if (tid < NBB) {
        float s = 0.0f;
        for (int j = 0; j < NBB; ++j) s += sf2[tid * NBB + j] * sz[j];
        swv[tid] = 1.0f / (1.0f + expf(-s));
    }
    __syncthreads();
    if (w == 0) {
        float va = (lane < NBB) ? swv[lane] : -1e30f;
        float vb = (lane + 64 < NBB) ? swv[lane + 64] : -1e30f;
        const int ia = lane, ib = lane + 64;
        for (int kk = 0; kk < KK; ++kk) {
            float v = va; int idx = ia;
            if (vb > v) { v = vb; idx = ib; }
#pragma unroll
            for (int m = 1; m < 64; m <<= 1) {
                const float ov = __shfl_xor(v, m);
                const int oi = __shfl_xor(idx, m);
                if (ov > v || (ov == v && oi < idx)) { v = ov; idx = oi; }
            }
            if (lane == 0) sidx[kk] = idx;
            if (ia == idx) va = -1e30f;
            if (ib == idx) vb = -1e30f;
        }
    }
    __syncthreads();

    for (int i = tid; i < KK * 136; i += 128) {
        const int k = i / 136;
        const int c4 = i - k * 136;
        const int n = sidx[k];
        const int shift = (c4 < 68) ? -1 : 0;
        float ax = 0.f, ay = 0.f, az = 0.f, aw = 0.f;
#pragma unroll
        for (int i2 = 0; i2 < 3; ++i2) {
            const int ttr = 3 * n + i2 + shift;
            if (ttr >= 0) {
                const float4 xv = x4[((size_t)b * TT + ttr) * 136 + c4];
                const float4 pv = p4[(size_t)ttr * 136 + c4];
                ax += xv.x + pv.x; ay += xv.y + pv.y; az += xv.z + pv.z; aw += xv.w + pv.w;
            }
        }
        const float inv3 = 1.0f / 3.0f;
        const float4 a = make_float4(ax * inv3, ay * inv3, az * inv3, aw * inv3);
        *(float4*)&st[k][c4 * 4] = a;
        ((float4*)t)[((size_t)b * KK + k) * 136 + c4] = a;
    }
    __syncthreads();

    for (int k = w; k < KK; k += 2) {
        float s = 0.0f, s2 = 0.0f;
        for (int c = lane; c < CC; c += 64) { const float v = st[k][c]; s += v; s2 += v * v; }
#pragma unroll
        for (int off = 32; off; off >>= 1) {
            s += __shfl_xor(s, off);
            s2 += __shfl_xor(s2, off);
        }
        const float m = s / (float)CC;
        const float inv = rsqrtf(s2 / (float)CC - m * m + EPSF);
        for (int c4 = lane; c4 < 136; c4 += 64) {
            const float4 v = *(const float4*)&st[k][c4 * 4];
            const float4 gv = ((const float4*)ln1g)[c4];
            const float4 bv = ((const float4*)ln1b)[c4];
            ushort4 o;
            o.x = f2bu((v.x - m) * inv * gv.x + bv.x);
            o.y = f2bu((v.y - m) * inv * gv.y + bv.y);
            o.z = f2bu((v.z - m) * inv * gv.z + bv.z);
            o.w = f2bu((v.w - m) * inv * gv.w + bv.w);
            ((ushort4*)hb)[((size_t)b * KK + k) * 136 + c4] = o;
        }
    }
}

// ---------------------------------------------------------------------------
// bf16 MFMA GEMM, BK=64, 128x128 tile, 4 waves (2x2).
// LNS=1: A is f32 (t) normalized on the fly using precomputed partial stats
//        (NPART partials per row, summed in a prologue).
// STATS=1: epilogue accumulates per-row (sum, sum^2) of output into
//        deterministic per-(coltile,wave) partial slots.
// ---------------------------------------------------------------------------
template <int LNS, int ACT, int RES, int STATS, int OBF>
__global__ __launch_bounds__(256) void gemm_mfma_kernel(
    const void* __restrict__ Xv,            // LNS ? f32 MxK : bf16 MxK
    const unsigned short* __restrict__ W,   // bf16 N x K
    const float* __restrict__ bias,         // N
    const float* __restrict__ Rr,           // M x N f32 residual or null
    const float* __restrict__ lng,          // K (LNS)
    const float* __restrict__ lnb,          // K (LNS)
    const float* __restrict__ Sin,          // NPART*M*2 partial stats (LNS)
    float* __restrict__ Sout,               // NPART*M*2 partial stats (STATS)
    void* __restrict__ Y,                   // f32 or bf16
    int M, int N, int Kd)
{
    const int bm = blockIdx.y * 128;
    const int bn = blockIdx.x * 128;
    const int tid = threadIdx.x;
    const int K8 = Kd >> 3;    // uint4 (8 bf16 / 8 f32) chunks per row
    const int K4 = Kd >> 2;    // float4 per row (LNS)

    __shared__ __align__(16) short As[128][72];
    __shared__ __align__(16) short Bs[128][72];
    __shared__ __align__(16) float sgb[LNS ? 2 * CC + 256 : 1];
    float* sg = sgb;                       // CC
    float* sb = sgb + CC;                  // CC
    float* smean_l = sgb + 2 * CC;         // 128
    float* sinv_l = sgb + 2 * CC + 128;    // 128

    const int r0 = tid >> 2;           // rows 0..63
    const int c0 = tid & 3;            // chunk slot 0..3 (of 8 per 64-k step)
    const int r1 = r0 + 64;            // rows 64..127
    const int wid = tid >> 6;
    const int lane = tid & 63;
    const int wm = (wid >> 1) * 64;
    const int wn = (wid & 1) * 64;
    const int l16 = lane & 15;
    const int l4 = lane >> 4;
    const int koff = l4 * 8;

    if constexpr (LNS) {
        for (int i = tid; i < 136; i += 256) {
            ((float4*)sg)[i] = ((const float4*)lng)[i];
            ((float4*)sb)[i] = ((const float4*)lnb)[i];
        }
        if (tid < 128) {
            const int row = bm + tid;
            float s = 0.f, s2 = 0.f;
#pragma unroll
            for (int p = 0; p < NPART; ++p) {
                s += Sin[(size_t)p * (MTOK * 2) + row * 2];
                s2 += Sin[(size_t)p * (MTOK * 2) + row * 2 + 1];
            }
            const float mm = s / (float)CC;
            smean_l[tid] = mm;
            sinv_l[tid] = rsqrtf(s2 / (float)CC - mm * mm + EPSF);
        }
        __syncthreads();
    }

    f32x4 acc[4][4] = {};

    const uint4* Wu = (const uint4*)W;
    const int wr0 = min(bn + r0, N - 1);
    const int wr1 = min(bn + r1, N - 1);

    const uint4 zz = {0u, 0u, 0u, 0u};
    const float4 fz = make_float4(0.f, 0.f, 0.f, 0.f);

    // prefetch registers
    uint4 a00, a01, a10, a11;                     // bf16 A path
    float4 fA[8];                                  // f32 A path (LNS)
    uint4 b00, b01, b10, b11;
    {
        const int k1 = c0, k2 = c0 + 4;
        if constexpr (LNS) {
            const float4* Xf = (const float4*)Xv;
            const size_t ro0 = (size_t)(bm + r0) * K4;
            const size_t ro1 = (size_t)(bm + r1) * K4;
            fA[0] = (k1 < K8) ? Xf[ro0 + 2 * k1] : fz;
            fA[1] = (k1 < K8) ? Xf[ro0 + 2 * k1 + 1] : fz;
            fA[2] = (k2 < K8) ? Xf[ro0 + 2 * k2] : fz;
            fA[3] = (k2 < K8) ? Xf[ro0 + 2 * k2 + 1] : fz;
            fA[4] = (k1 < K8) ? Xf[ro1 + 2 * k1] : fz;
            fA[5] = (k1 < K8) ? Xf[ro1 + 2 * k1 + 1] : fz;
            fA[6] = (k2 < K8) ? Xf[ro1 + 2 * k2] : fz;
            fA[7] = (k2 < K8) ? Xf[ro1 + 2 * k2 + 1] : fz;
        } else {
            const uint4* Xu = (const uint4*)Xv;
            a00 = (k1 < K8) ? Xu[(size_t)(bm + r0) * K8 + k1] : zz;
            a01 = (k2 < K8) ? Xu[(size_t)(bm + r0) * K8 + k2] : zz;
            a10 = (k1 < K8) ? Xu[(size_t)(bm + r1) * K8 + k1] : zz;
            a11 = (k2 < K8) ? Xu[(size_t)(bm + r1) * K8 + k2] : zz;
        }
        b00 = (k1 < K8) ? Wu[(size_t)wr0 * K8 + k1] : zz;
        b01 = (k2 < K8) ? Wu[(size_t)wr0 * K8 + k2] : zz;
        b10 = (k1 < K8) ? Wu[(size_t)wr1 * K8 + k1] : zz;
        b11 = (k2 < K8) ? Wu[(size_t)wr1 * K8 + k2] : zz;
    }

    const int nk = (Kd + 63) >> 6;
    for (int kt = 0; kt < nk; ++kt) {
        __syncthreads();
        if constexpr (LNS) {
            const bool w1 = (kt * 8 + c0) < K8;
            const bool w2 = (kt * 8 + c0 + 4) < K8;
            const float m0 = smean_l[r0], i0 = sinv_l[r0];
            const float m1 = smean_l[r1], i1 = sinv_l[r1];
            const int cb1 = kt * 64 + c0 * 8;
            const int cb2 = cb1 + 32;
            const ushort4 z4 = {0, 0, 0, 0};
            *(ushort4*)&As[r0][c0 * 8]           = w1 ? norm4(fA[0], m0, i0, sg, sb, cb1) : z4;
            *(ushort4*)&As[r0][c0 * 8 + 4]       = w1 ? norm4(fA[1], m0, i0, sg, sb, cb1 + 4) : z4;
            *(ushort4*)&As[r0][(c0 + 4) * 8]     = w2 ? norm4(fA[2], m0, i0, sg, sb, cb2) : z4;
            *(ushort4*)&As[r0][(c0 + 4) * 8 + 4] = w2 ? norm4(fA[3], m0, i0, sg, sb, cb2 + 4) : z4;
            *(ushort4*)&As[r1][c0 * 8]           = w1 ? norm4(fA[4], m1, i1, sg, sb, cb1) : z4;
            *(ushort4*)&As[r1][c0 * 8 + 4]       = w1 ? norm4(fA[5], m1, i1, sg, sb, cb1 + 4) : z4;
            *(ushort4*)&As[r1][(c0 + 4) * 8]     = w2 ? norm4(fA[6], m1, i1, sg, sb, cb2) : z4;
            *(ushort4*)&As[r1][(c0 + 4) * 8 + 4] = w2 ? norm4(fA[7], m1, i1, sg, sb, cb2 + 4) : z4;
        } else {
            *(uint4*)&As[r0][c0 * 8]       = a00;
            *(uint4*)&As[r0][(c0 + 4) * 8] = a01;
            *(uint4*)&As[r1][c0 * 8]       = a10;
            *(uint4*)&As[r1][(c0 + 4) * 8] = a11;
        }
        *(uint4*)&Bs[r0][c0 * 8]       = b00;
        *(uint4*)&Bs[r0][(c0 + 4) * 8] = b01;
        *(uint4*)&Bs[r1][c0 * 8]       = b10;
        *(uint4*)&Bs[r1][(c0 + 4) * 8] = b11;
        __syncthreads();

        if (kt + 1 < nk) {
            const int k1 = (kt + 1) * 8 + c0;
            const int k2 = k1 + 4;
            if constexpr (LNS) {
                const float4* Xf = (const float4*)Xv;
                const size_t ro0 = (size_t)(bm + r0) * K4;
                const size_t ro1 = (size_t)(bm + r1) * K4;
                fA[0] = (k1 < K8) ? Xf[ro0 + 2 * k1] : fz;
                fA[1] = (k1 < K8) ? Xf[ro0 + 2 * k1 + 1] : fz;
                fA[2] = (k2 < K8) ? Xf[ro0 + 2 * k2] : fz;
                fA[3] = (k2 < K8) ? Xf[ro0 + 2 * k2 + 1] : fz;
                fA[4] = (k1 < K8) ? Xf[ro1 + 2 * k1] : fz;
                fA[5] = (k1 < K8) ? Xf[ro1 + 2 * k1 + 1] : fz;
                fA[6] = (k2 < K8) ? Xf[ro1 + 2 * k2] : fz;
                fA[7] = (k2 < K8) ? Xf[ro1 + 2 * k2 + 1] : fz;
            } else {
                const uint4* Xu = (const uint4*)Xv;
                a00 = (k1 < K8) ? Xu[(size_t)(bm + r0) * K8 + k1] : zz;
                a01 = (k2 < K8) ? Xu[(size_t)(bm + r0) * K8 + k2] : zz;
                a10 = (k1 < K8) ? Xu[(size_t)(bm + r1) * K8 + k1] : zz;
                a11 = (k2 < K8) ? Xu[(size_t)(bm + r1) * K8 + k2] : zz;
            }
            b00 = (k1 < K8) ? Wu[(size_t)wr0 * K8 + k1] : zz;
            b01 = (k2 < K8) ? Wu[(size_t)wr0 * K8 + k2] : zz;
            b10 = (k1 < K8) ? Wu[(size_t)wr1 * K8 + k1] : zz;
            b11 = (k2 < K8) ? Wu[(size_t)wr1 * K8 + k2] : zz;
        }

#pragma unroll
        for (int kh = 0; kh < 2; ++kh) {
            bf16x8 af[4], bf[4];
#pragma unroll
            for (int mf = 0; mf < 4; ++mf)
                af[mf] = *(const bf16x8*)&As[wm + mf * 16 + l16][kh * 32 + koff];
#pragma unroll
            for (int nf = 0; nf < 4; ++nf)
                bf[nf] = *(const bf16x8*)&Bs[wn + nf * 16 + l16][kh * 32 + koff];
#pragma unroll
            for (int mf = 0; mf < 4; ++mf)
#pragma unroll
                for (int nf = 0; nf < 4; ++nf)
                    acc[mf][nf] = __builtin_amdgcn_mfma_f32_16x16x32_bf16(af[mf], bf[nf], acc[mf][nf], 0, 0, 0);
        }
    }

    // epilogue (+ optional per-row stats accumulation)
    float ssum[16], ssq[16];
    if constexpr (STATS) {
#pragma unroll
        for (int q = 0; q < 16; ++q) { ssum[q] = 0.f; ssq[q] = 0.f; }
    }

#pragma unroll
    for (int nf = 0; nf < 4; ++nf) {
        const int col = bn + wn + nf * 16 + l16;
        const bool ok = col < N;
        const float bs = ok ? bias[col] : 0.0f;
#pragma unroll
        for (int mf = 0; mf < 4; ++mf) {
#pragma unroll
            for (int j = 0; j < 4; ++j) {
                const int row = bm + wm + mf * 16 + l4 * 4 + j;
                float v = acc[mf][nf][j] + bs;
                if (ACT == 1) v = 0.5f * v * (1.0f + erff(v * 0.70710678118654752f));
                if (ok) {
                    if (RES) v += Rr[(size_t)row * N + col];
                    if (OBF) ((unsigned short*)Y)[(size_t)row * N + col] = f2bu(v);
                    else     ((float*)Y)[(size_t)row * N + col] = v;
                    if constexpr (STATS) {
                        ssum[mf * 4 + j] += v;
                        ssq[mf * 4 + j] += v * v;
                    }
                }
            }
        }
    }

    if constexpr (STATS) {
#pragma unroll
        for (int q = 0; q < 16; ++q) {
            float a = ssum[q], bq = ssq[q];
#pragma unroll
            for (int m = 1; m < 16; m <<= 1) {
                a += __shfl_xor(a, m);
                bq += __shfl_xor(bq, m);
            }
            if (l16 == 0) {
                const int row_l = wm + (q >> 2) * 16 + l4 * 4 + (q & 3);
                const int p = ((bn >> 7) * 2) + (wn >> 6);
                float* dst = Sout + (size_t)p * (MTOK * 2) + (size_t)(bm + row_l) * 2;
                dst[0] = a;
                dst[1] = bq;
            }
        }
    }
}

// ---------------------------------------------------------------------------
// Attention (R5, unchanged): per block b; 8 waves = 8 heads
// ---------------------------------------------------------------------------
__global__ __launch_bounds__(512) void attn_kernel(
    const unsigned short* __restrict__ qkv,  // B*6*1632 bf16
    __hip_bfloat16* __restrict__ o)          // B*6*544 bf16
{
    const int b = blockIdx.x;
    __shared__ __align__(16) float sq[KK * 3 * CC];
    __shared__ float sp[HH][40];
    const int tid = threadIdx.x;

    const uint4* src4 = (const uint4*)(qkv + (size_t)b * KK * 3 * CC);
    for (int i = tid; i < (KK * 3 * CC) / 8; i += 512) {
        const uint4 u = src4[i];
        float4 f0, f1;
        f0.x = b2f_lo(u.x); f0.y = b2f_hi(u.x);
        f0.z = b2f_lo(u.y); f0.w = b2f_hi(u.y);
        f1.x = b2f_lo(u.z); f1.y = b2f_hi(u.z);
        f1.z = b2f_lo(u.w); f1.w = b2f_hi(u.w);
        ((float4*)sq)[2 * i] = f0;
        ((float4*)sq)[2 * i + 1] = f1;
    }
    __syncthreads();

    const int h = tid >> 6;
    const int lane = tid & 63;
    const float scl = rsqrtf((float)HD);

    if (lane < KK * KK) {
        const int n = lane / KK, m = lane - (lane / KK) * KK;
        const float* qp = &sq[n * (3 * CC) + 0 * CC + h * HD];
        const float* kp = &sq[m * (3 * CC) + 1 * CC + h * HD];
        float s = 0.0f;
#pragma unroll 4
        for (int d = 0; d < HD; ++d) s += qp[d] * kp[d];
        sp[h][lane] = s * scl;
    }
    __syncthreads();
    if (lane < KK) {
        const int n = lane;
        float mx = -1e30f;
#pragma unroll
        for (int m = 0; m < KK; ++m) mx = fmaxf(mx, sp[h][n * KK + m]);
        float e[KK];
        float sum = 0.0f;
#pragma unroll
        for (int m = 0; m < KK; ++m) { e[m] = expf(sp[h][n * KK + m] - mx); sum += e[m]; }
        const float inv = 1.0f / sum;
#pragma unroll
        for (int m = 0; m < KK; ++m) sp[h][n * KK + m] = e[m] * inv;
    }
    __syncthreads();
    for (int i = tid; i < KK * CC; i += 512) {
        const int n = i / CC;
        const int cd = i - n * CC;
        const int hh = cd / HD;
        const int d = cd - hh * HD;
        float acc = 0.0f;
#pragma unroll
        for (int m = 0; m < KK; ++m)
            acc += sp[hh][n * KK + m] * sq[m * (3 * CC) + 2 * CC + hh * HD + d];
        o[(size_t)b * KK * CC + i] = f2b(acc);
    }
}

// ---------------------------------------------------------------------------
// Final: LN(t) with lnf using precomputed partial stats + weighted sum
// ---------------------------------------------------------------------------
__global__ __launch_bounds__(256) void final_kernel(
    const float* __restrict__ t, const float* __restrict__ g,
    const float* __restrict__ bta, const float* __restrict__ wm2w,
    const float* __restrict__ wm2b, const float* __restrict__ Sin,
    float* __restrict__ out)
{
    const int b = blockIdx.x;
    const int tid = threadIdx.x;
    __shared__ float st[KK][CC];
    __shared__ float sm[KK], si[KK];
    const float* tb = t + (size_t)b * KK * CC;
    for (int i = tid; i < KK * CC; i += 256) st[i / CC][i % CC] = tb[i];
    if (tid < KK) {
        const int row = b * KK + tid;
        float s = 0.f, s2 = 0.f;
#pragma unroll
        for (int p = 0; p < NPART; ++p) {
            s += Sin[(size_t)p * (MTOK * 2) + row * 2];
            s2 += Sin[(size_t)p * (MTOK * 2) + row * 2 + 1];
        }
        const float m = s / (float)CC;
        sm[tid] = m;
        si[tid] = rsqrtf(s2 / (float)CC - m * m + EPSF);
    }
    __syncthreads();
    const float w0 = wm2w[0], w1 = wm2w[1], w2 = wm2w[2], w3 = wm2w[3], w4 = wm2w[4], w5 = wm2w[5];
    const float wb = wm2b[0];
    for (int c = tid; c < CC; c += 256) {
        const float gg = g[c], bb = bta[c];
        float acc = wb;
        acc += w0 * ((st[0][c] - sm[0]) * si[0] * gg + bb);
        acc += w1 * ((st[1][c] - sm[1]) * si[1] * gg + bb);
        acc += w2 * ((st[2][c] - sm[2]) * si[2] * gg + bb);
        acc += w3 * ((st[3][c] - sm[3]) * si[3] * gg + bb);
        acc += w4 * ((st[4][c] - sm[4]) * si[4] * gg + bb);
        acc += w5 * ((st[5][c] - sm[5]) * si[5] * gg + bb);
        out[(size_t)b * CC + c] = acc;
    }
}

// ---------------------------------------------------------------------------
extern "C" void kernel_launch(void* const* d_in, const int* in_sizes, int n_in,
                              void* d_out, int out_size, void* d_ws, size_t ws_size,
                              hipStream_t stream)
{
    const float* x      = (const float*)d_in[0];
    const float* pos    = (const float*)d_in[1];
    const float* fc1_w  = (const float*)d_in[2];
    const float* fc2_w  = (const float*)d_in[3];
    const float* ln1_g  = (const float*)d_in[4];
    const float* ln1_b  = (const float*)d_in[5];
    const float* qkv_w  = (const float*)d_in[6];
    const float* qkv_b  = (const float*)d_in[7];
    const float* proj_w = (const float*)d_in[8];
    const float* proj_b = (const float*)d_in[9];
    const float* ln2_g  = (const float*)d_in[10];
    const float* ln2_b  = (const float*)d_in[11];
    const float* mfc1_w = (const float*)d_in[12];
    const float* mfc1_b = (const float*)d_in[13];
    const float* mfc2_w = (const float*)d_in[14];
    const float* mfc2_b = (const float*)d_in[15];
    const float* lnf_g  = (const float*)d_in[16];
    const float* lnf_b  = (const float*)d_in[17];
    const float* wm2_w  = (const float*)d_in[18];
    const float* wm2_b  = (const float*)d_in[19];

    float* ws = (float*)d_ws;
    float* L    = ws;                              // 124416
    float* R    = L + 124416;                      // 124416
    float* pLR  = R + 124416;                      // 486 (+pad)
    float* S1   = pLR + 512;                       // NPART*3072*2 = 61440
    float* S2   = S1 + NPART * MTOK * 2;
    float* S3   = S2 + NPART * MTOK * 2;
    float* S4   = S3 + NPART * MTOK * 2;
    float* t    = S4 + NPART * MTOK * 2;           // 3072*544 f32
    unsigned short* qkvb = (unsigned short*)(t + (size_t)MTOK * CC);
    unsigned short* hb  = qkvb + (size_t)MTOK * 3 * CC;
    unsigned short* ob  = hb + (size_t)MTOK * CC;
    unsigned short* gb  = ob + (size_t)MTOK * CC;
    unsigned short* wbf = gb + (size_t)MTOK * HID;

    unsigned short* wqkv = wbf;                         // 2 x (1632*544)
    unsigned short* wprj = wbf + 1775616;               // 2 x (544*544)
    unsigned short* wf1  = wbf + 2367488;               // 2 x (1088*544)
    unsigned short* wf2  = wbf + 3551232;               // 2 x (544*1088)

    bw_kernel<<<BW_GRID, 256, 0, stream>>>(
        x, pos, qkv_w, proj_w, mfc1_w, mfc2_w, wbf, L, R, pLR);

    select_kernel<<<BB, 128, 0, stream>>>(
        L, R, pLR, fc1_w, fc2_w, x, pos, ln1_g, ln1_b, t, hb);

    float* Sln2[2] = {S1, S3};
    float* Sln1n[2] = {S2, S4};   // written by mfc2 of layer i
    for (int i = 0; i < DEPTH; ++i) {
        // qkv: layer 0 reads hb (bf16); layer 1 reads t via LNS(stats from S2)
        if (i == 0) {
            gemm_mfma_kernel<0, 0, 0, 0, 1><<<dim3(13, 24), 256, 0, stream>>>(
                hb, wqkv, qkv_b, nullptr, nullptr, nullptr, nullptr, nullptr,
                qkvb, MTOK, 3 * CC, CC);
        } else {
            gemm_mfma_kernel<1, 0, 0, 0, 1><<<dim3(13, 24), 256, 0, stream>>>(
                t, wqkv + (size_t)i * 1632 * 544, qkv_b + (size_t)i * 3 * CC,
                nullptr, ln1_g + i * CC, ln1_b + i * CC, Sln1n[0], nullptr,
                qkvb, MTOK, 3 * CC, CC);
        }
        attn_kernel<<<BB, 512, 0, stream>>>(qkvb, (__hip_bfloat16*)ob);
        // proj: +res -> t, epilogue stats -> Sln2[i]
        gemm_mfma_kernel<0, 0, 1, 1, 0><<<dim3(5, 24), 256, 0, stream>>>(
            ob, wprj + (size_t)i * 544 * 544, proj_b + (size_t)i * CC,
            t, nullptr, nullptr, nullptr, Sln2[i], t, MTOK, CC, CC);
        // mfc1: A = LN2(t) via stats, gelu -> gb bf16
        gemm_mfma_kernel<1, 1, 0, 0, 1><<<dim3(9, 24), 256, 0, stream>>>(
            t, wf1 + (size_t)i * HID * 544, mfc1_b + (size_t)i * HID,
            nullptr, ln2_g + i * CC, ln2_b + i * CC, Sln2[i], nullptr,
            gb, MTOK, HID, CC);
        // mfc2: +res -> t, epilogue stats -> S2 (i=0) / S4 (i=1)
        gemm_mfma_kernel<0, 0, 1, 1, 0><<<dim3(5, 24), 256, 0, stream>>>(
            gb, wf2 + (size_t)i * 544 * HID, mfc2_b + (size_t)i * CC,
            t, nullptr, nullptr, nullptr, Sln1n[i], t, MTOK, CC, HID);
    }

    final_kernel<<<BB, 256, 0, stream>>>(t, lnf_g, lnf_b, wm2_w, wm2_b, S4, (float*)d_out);
}

// Round 11
// 236.143 us; speedup vs baseline: 1.8120x; 1.8120x over previous
//
#include <hip/hip_runtime.h>
#include <hip/hip_bf16.h>
#include <math.h>

// Problem constants
#define TT 243
#define CC 544            // J*IC
#define NBB 81            // T/BS
#define KK 6
#define HH 8
#define HD 68             // C/H
#define DEPTH 2
#define HID 1088          // 2*C
#define BB 512
#define MTOK 3072         // B*K tokens
#define EPSF 1e-6f

typedef __attribute__((ext_vector_type(8))) short bf16x8;
typedef __attribute__((ext_vector_type(4))) float f32x4;

__device__ __forceinline__ __hip_bfloat16 f2b(float f) { return __float2bfloat16(f); }
__device__ __forceinline__ unsigned short f2bu(float f) {
    __hip_bfloat16 h = __float2bfloat16(f);
    return *(unsigned short*)&h;
}
__device__ __forceinline__ float b2f_lo(unsigned int u) { return __uint_as_float(u << 16); }
__device__ __forceinline__ float b2f_hi(unsigned int u) { return __uint_as_float(u & 0xffff0000u); }

// weight conversion segment ends (float4-index space): qkv | proj | mfc1 | mfc2
#define E0 443904      // 2*1632*544/4
#define E1 591872      // +2*544*544/4
#define E2 887808      // +2*1088*544/4
#define E3 1183744     // +2*544*1088/4

// bw_kernel block ranges
#define RS_BLOCKS 3888            // 3888*32 rows = 124416 = 512*243
#define PS_BLOCKS 8               // 8*32 = 256 >= 243 pos rows
#define WC_BLOCKS 4624            // E3/256
#define BW_GRID (RS_BLOCKS + PS_BLOCKS + WC_BLOCKS)

// ---------------------------------------------------------------------------
// bw_kernel: pure-bandwidth pass (proven R5 version, unchanged)
// ---------------------------------------------------------------------------
__global__ __launch_bounds__(256, 4) void bw_kernel(
    const float* __restrict__ x,     // B*T*C
    const float* __restrict__ pos,   // T*C
    const float* __restrict__ qkvw, const float* __restrict__ projw,
    const float* __restrict__ mfc1w, const float* __restrict__ mfc2w,
    unsigned short* __restrict__ wbf,
    float* __restrict__ L,           // B*T  (x-only)
    float* __restrict__ R,           // B*T  (x-only)
    float* __restrict__ pLR)         // 2*T: pL | pR
{
    const int blk = blockIdx.x;
    const int tid = threadIdx.x;

    if (blk < RS_BLOCKS) {
        const int w = tid >> 6;
        const int lane = tid & 63;
        const int oct = lane & 7;
        const int rsub = lane >> 3;
        const int r = (blk * 4 + w) * 8 + rsub;          // 0..124415
        const float4* xr = (const float4*)x + (size_t)r * 136;
        float4 xs[17];
#pragma unroll
        for (int j = 0; j < 17; ++j) xs[j] = xr[oct + j * 8];
        float aL = 0.0f, aR = 0.0f;
#pragma unroll
        for (int j = 0; j < 17; ++j) {
            const float s = (xs[j].x + xs[j].y) + (xs[j].z + xs[j].w);
            if (j < 8) aL += s;
            else if (j == 8) { if (oct < 4) aL += s; else aR += s; }
            else aR += s;
        }
#pragma unroll
        for (int m = 1; m < 8; m <<= 1) {
            aL += __shfl_xor(aL, m);
            aR += __shfl_xor(aR, m);
        }
        if (oct == 0) { L[r] = aL; R[r] = aR; }
        return;
    }

    if (blk < RS_BLOCKS + PS_BLOCKS) {
        const int w = tid >> 6;
        const int lane = tid & 63;
        const int oct = lane & 7;
        const int rsub = lane >> 3;
        const int r = (blk - RS_BLOCKS) * 32 + w * 8 + rsub;   // 0..255
        const int rc = (r < TT) ? r : (TT - 1);
        const float4* pr = (const float4*)pos + (size_t)rc * 136;
        float4 xs[17];
#pragma unroll
        for (int j = 0; j < 17; ++j) xs[j] = pr[oct + j * 8];
        float aL = 0.0f, aR = 0.0f;
#pragma unroll
        for (int j = 0; j < 17; ++j) {
            const float s = (xs[j].x + xs[j].y) + (xs[j].z + xs[j].w);
            if (j < 8) aL += s;
            else if (j == 8) { if (oct < 4) aL += s; else aR += s; }
            else aR += s;
        }
#pragma unroll
        for (int m = 1; m < 8; m <<= 1) {
            aL += __shfl_xor(aL, m);
            aR += __shfl_xor(aR, m);
        }
        if (oct == 0 && r < TT) { pLR[r] = aL; pLR[TT + r] = aR; }
        return;
    }

    // ---- weight conversion ----
    const int i = (blk - RS_BLOCKS - PS_BLOCKS) * 256 + tid;
    if (i < E3) {
        float4 v;
        if (i < E0)      v = ((const float4*)qkvw)[i];
        else if (i < E1) v = ((const float4*)projw)[i - E0];
        else if (i < E2) v = ((const float4*)mfc1w)[i - E1];
        else             v = ((const float4*)mfc2w)[i - E2];
        ushort4 o;
        o.x = f2bu(v.x); o.y = f2bu(v.y); o.z = f2bu(v.z); o.w = f2bu(v.w);
        ((ushort4*)wbf)[i] = o;
    }
}

// ---------------------------------------------------------------------------
// select: y0, MLP, top-6, gather + fused ln1_0 -> hb (R5, unchanged)
// ---------------------------------------------------------------------------
__global__ __launch_bounds__(128) void select_kernel(
    const float* __restrict__ L, const float* __restrict__ R,
    const float* __restrict__ pLR,
    const float* __restrict__ fc1, const float* __restrict__ fc2,
    const float* __restrict__ x, const float* __restrict__ pos,
    const float* __restrict__ ln1g, const float* __restrict__ ln1b,
    float* __restrict__ t,           // B*6*544 f32
    unsigned short* __restrict__ hb) // B*6*544 bf16 (= ln1_0 output)
{
    const int b = blockIdx.x;
    const int tid = threadIdx.x;
    __shared__ float sf1[NBB * NBB];
    __shared__ float sf2[NBB * NBB];
    __shared__ float sy[NBB], sz[NBB], swv[NBB];
    __shared__ int sidx[KK];
    __shared__ __align__(16) float st[KK][CC];

    const int w = tid >> 6;
    const int lane = tid & 63;
    const float4* x4 = (const float4*)x;
    const float4* p4 = (const float4*)pos;

    for (int i = tid; i < NBB * NBB; i += 128) {
        sf1[i] = fc1[i];
        sf2[i] = fc2[i];
    }

    if (tid < NBB) {
        const int n = tid;
        const float* Lb = L + (size_t)b * TT;
        const float* Rb = R + (size_t)b * TT;
        const float* pL = pLR;
        const float* pR = pLR + TT;
        float s = Lb[3 * n] + Lb[3 * n + 1] + Rb[3 * n] + Rb[3 * n + 1] + Rb[3 * n + 2]
                + pL[3 * n] + pL[3 * n + 1] + pR[3 * n] + pR[3 * n + 1] + pR[3 * n + 2];
        if (n > 0) s += Lb[3 * n - 1] + pL[3 * n - 1];
        sy[n] = s * (1.0f / (3.0f * (float)CC));
    }
    __syncthreads();
    if (tid < NBB) {
        float s = 0.0f;
        for (int j = 0; j < NBB; ++j) s += sf1[tid * NBB + j] * sy[j];
        sz[tid] = fmaxf(s, 0.0f);
    }
    __syncthreads();
    if (tid < NBB) {
        float s = 0.0f;
        for (int j = 0; j < NBB; ++j) s += sf2[tid * NBB + j] * sz[j];
        swv[tid] = 1.0f / (1.0f + expf(-s));
    }
    __syncthreads();
    if (w == 0) {
        float va = (lane < NBB) ? swv[lane] : -1e30f;
        float vb = (lane + 64 < NBB) ? swv[lane + 64] : -1e30f;
        const int ia = lane, ib = lane + 64;
        for (int kk = 0; kk < KK; ++kk) {
            float v = va; int idx = ia;
            if (vb > v) { v = vb; idx = ib; }
#pragma unroll
            for (int m = 1; m < 64; m <<= 1) {
                const float ov = __shfl_xor(v, m);
                const int oi = __shfl_xor(idx, m);
                if (ov > v || (ov == v && oi < idx)) { v = ov; idx = oi; }
            }
            if (lane == 0) sidx[kk] = idx;
            if (ia == idx) va = -1e30f;
            if (ib == idx) vb = -1e30f;
        }
    }
    __syncthreads();

    for (int i = tid; i < KK * 136; i += 128) {
        const int k = i / 136;
        const int c4 = i - k * 136;
        const int n = sidx[k];
        const int shift = (c4 < 68) ? -1 : 0;
        float ax = 0.f, ay = 0.f, az = 0.f, aw = 0.f;
#pragma unroll
        for (int i2 = 0; i2 < 3; ++i2) {
            const int ttr = 3 * n + i2 + shift;
            if (ttr >= 0) {
                const float4 xv = x4[((size_t)b * TT + ttr) * 136 + c4];
                const float4 pv = p4[(size_t)ttr * 136 + c4];
                ax += xv.x + pv.x; ay += xv.y + pv.y; az += xv.z + pv.z; aw += xv.w + pv.w;
            }
        }
        const float inv3 = 1.0f / 3.0f;
        const float4 a = make_float4(ax * inv3, ay * inv3, az * inv3, aw * inv3);
        *(float4*)&st[k][c4 * 4] = a;
        ((float4*)t)[((size_t)b * KK + k) * 136 + c4] = a;
    }
    __syncthreads();

    for (int k = w; k < KK; k += 2) {
        float s = 0.0f, s2 = 0.0f;
        for (int c = lane; c < CC; c += 64) { const float v = st[k][c]; s += v; s2 += v * v; }
#pragma unroll
        for (int off = 32; off; off >>= 1) {
            s += __shfl_xor(s, off);
            s2 += __shfl_xor(s2, off);
        }
        const float m = s / (float)CC;
        const float inv = rsqrtf(s2 / (float)CC - m * m + EPSF);
        for (int c4 = lane; c4 < 136; c4 += 64) {
            const float4 v = *(const float4*)&st[k][c4 * 4];
            const float4 gv = ((const float4*)ln1g)[c4];
            const float4 bv = ((const float4*)ln1b)[c4];
            ushort4 o;
            o.x = f2bu((v.x - m) * inv * gv.x + bv.x);
            o.y = f2bu((v.y - m) * inv * gv.y + bv.y);
            o.z = f2bu((v.z - m) * inv * gv.z + bv.z);
            o.w = f2bu((v.w - m) * inv * gv.w + bv.w);
            ((ushort4*)hb)[((size_t)b * KK + k) * 136 + c4] = o;
        }
    }
}

// ---------------------------------------------------------------------------
// LayerNorm over last dim (544): 4 rows/block, wave per row (R5, unchanged)
// ---------------------------------------------------------------------------
__global__ __launch_bounds__(256) void ln_bf16_kernel(
    const float* __restrict__ X, const float* __restrict__ g,
    const float* __restrict__ bta, unsigned short* __restrict__ Y)
{
    const int row = blockIdx.x * 4 + (threadIdx.x >> 6);
    const int lane = threadIdx.x & 63;
    const float4* xr4 = (const float4*)(X + (size_t)row * CC);
    const float4 v0 = xr4[lane];
    const float4 v1 = xr4[lane + 64];
    float4 v2 = make_float4(0.f, 0.f, 0.f, 0.f);
    if (lane < 8) v2 = xr4[lane + 128];
    float s = (v0.x + v0.y + v0.z + v0.w) + (v1.x + v1.y + v1.z + v1.w)
            + (v2.x + v2.y + v2.z + v2.w);
    float s2 = (v0.x * v0.x + v0.y * v0.y + v0.z * v0.z + v0.w * v0.w)
             + (v1.x * v1.x + v1.y * v1.y + v1.z * v1.z + v1.w * v1.w)
             + (v2.x * v2.x + v2.y * v2.y + v2.z * v2.z + v2.w * v2.w);
#pragma unroll
    for (int off = 32; off; off >>= 1) {
        s += __shfl_xor(s, off);
        s2 += __shfl_xor(s2, off);
    }
    const float m = s / (float)CC;
    const float inv = rsqrtf(s2 / (float)CC - m * m + EPSF);
    ushort4* yr = (ushort4*)(Y + (size_t)row * CC);
    {
        const float4 gv = ((const float4*)g)[lane];
        const float4 bv = ((const float4*)bta)[lane];
        ushort4 o;
        o.x = f2bu((v0.x - m) * inv * gv.x + bv.x);
        o.y = f2bu((v0.y - m) * inv * gv.y + bv.y);
        o.z = f2bu((v0.z - m) * inv * gv.z + bv.z);
        o.w = f2bu((v0.w - m) * inv * gv.w + bv.w);
        yr[lane] = o;
    }
    {
        const float4 gv = ((const float4*)g)[lane + 64];
        const float4 bv = ((const float4*)bta)[lane + 64];
        ushort4 o;
        o.x = f2bu((v1.x - m) * inv * gv.x + bv.x);
        o.y = f2bu((v1.y - m) * inv * gv.y + bv.y);
        o.z = f2bu((v1.z - m) * inv * gv.z + bv.z);
        o.w = f2bu((v1.w - m) * inv * gv.w + bv.w);
        yr[lane + 64] = o;
    }
    if (lane < 8) {
        const float4 gv = ((const float4*)g)[lane + 128];
        const float4 bv = ((const float4*)bta)[lane + 128];
        ushort4 o;
        o.x = f2bu((v2.x - m) * inv * gv.x + bv.x);
        o.y = f2bu((v2.y - m) * inv * gv.y + bv.y);
        o.z = f2bu((v2.z - m) * inv * gv.z + bv.z);
        o.w = f2bu((v2.w - m) * inv * gv.w + bv.w);
        yr[lane + 128] = o;
    }
}

// ---------------------------------------------------------------------------
// bf16 MFMA GEMM, BK=64, 64x128 tile, 4 waves (2x2 of 32x64 each).
// Doubled grid parallelism vs 128x128 (proj/mfc2: 120 -> 240 blocks) and
// halved per-block latency. K-tail zero-padded in LDS (no MFMA guards).
// ---------------------------------------------------------------------------
template <int ACT, int RES, int OBF>
__global__ __launch_bounds__(256) void gemm_mfma_kernel(
    const unsigned short* __restrict__ X,   // bf16 M x K
    const unsigned short* __restrict__ W,   // bf16 N x K
    const float* __restrict__ bias,         // N
    const float* __restrict__ Rr,           // M x N (f32) or null
    void* __restrict__ Y,                   // f32 or bf16
    int M, int N, int Kd)
{
    const int bm = blockIdx.y * 64;
    const int bn = blockIdx.x * 128;
    const int tid = threadIdx.x;
    const int K8 = Kd >> 3;    // uint4 per row

    __shared__ __align__(16) short As[64][72];
    __shared__ __align__(16) short Bs[128][72];

    const int r0 = tid >> 2;           // A row 0..63, B row 0..63
    const int c0 = tid & 3;            // chunk slot 0..3 (of 8 per 64-k step)
    const int r1 = r0 + 64;            // B rows 64..127

    const uint4* Xu = (const uint4*)X;
    const uint4* Wu = (const uint4*)W;

    const int wid = tid >> 6;
    const int lane = tid & 63;
    const int wm = (wid >> 1) * 32;    // 0 or 32
    const int wn = (wid & 1) * 64;     // 0 or 64
    const int l16 = lane & 15;
    const int l4 = lane >> 4;          // 0..3
    const int koff = l4 * 8;

    f32x4 acc[2][4] = {};

    const int wr0 = min(bn + r0, N - 1);
    const int wr1 = min(bn + r1, N - 1);

    const uint4 zz = {0u, 0u, 0u, 0u};
    // staged chunks: A row r0 x {c0, c0+4}; B rows {r0, r1} x {c0, c0+4}
    uint4 a00, a01, b00, b01, b10, b11;
    {
        const int k1 = c0, k2 = c0 + 4;
        a00 = (k1 < K8) ? Xu[(size_t)(bm + r0) * K8 + k1] : zz;
        a01 = (k2 < K8) ? Xu[(size_t)(bm + r0) * K8 + k2] : zz;
        b00 = (k1 < K8) ? Wu[(size_t)wr0 * K8 + k1] : zz;
        b01 = (k2 < K8) ? Wu[(size_t)wr0 * K8 + k2] : zz;
        b10 = (k1 < K8) ? Wu[(size_t)wr1 * K8 + k1] : zz;
        b11 = (k2 < K8) ? Wu[(size_t)wr1 * K8 + k2] : zz;
    }

    const int nk = (Kd + 63) >> 6;
    for (int kt = 0; kt < nk; ++kt) {
        __syncthreads();
        *(uint4*)&As[r0][c0 * 8]       = a00;
        *(uint4*)&As[r0][(c0 + 4) * 8] = a01;
        *(uint4*)&Bs[r0][c0 * 8]       = b00;
        *(uint4*)&Bs[r0][(c0 + 4) * 8] = b01;
        *(uint4*)&Bs[r1][c0 * 8]       = b10;
        *(uint4*)&Bs[r1][(c0 + 4) * 8] = b11;
        __syncthreads();

        if (kt + 1 < nk) {
            const int k1 = (kt + 1) * 8 + c0;
            const int k2 = k1 + 4;
            a00 = (k1 < K8) ? Xu[(size_t)(bm + r0) * K8 + k1] : zz;
            a01 = (k2 < K8) ? Xu[(size_t)(bm + r0) * K8 + k2] : zz;
            b00 = (k1 < K8) ? Wu[(size_t)wr0 * K8 + k1] : zz;
            b01 = (k2 < K8) ? Wu[(size_t)wr0 * K8 + k2] : zz;
            b10 = (k1 < K8) ? Wu[(size_t)wr1 * K8 + k1] : zz;
            b11 = (k2 < K8) ? Wu[(size_t)wr1 * K8 + k2] : zz;
        }

#pragma unroll
        for (int kh = 0; kh < 2; ++kh) {
            bf16x8 af[2], bf[4];
#pragma unroll
            for (int mf = 0; mf < 2; ++mf)
                af[mf] = *(const bf16x8*)&As[wm + mf * 16 + l16][kh * 32 + koff];
#pragma unroll
            for (int nf = 0; nf < 4; ++nf)
                bf[nf] = *(const bf16x8*)&Bs[wn + nf * 16 + l16][kh * 32 + koff];
#pragma unroll
            for (int mf = 0; mf < 2; ++mf)
#pragma unroll
                for (int nf = 0; nf < 4; ++nf)
                    acc[mf][nf] = __builtin_amdgcn_mfma_f32_16x16x32_bf16(af[mf], bf[nf], acc[mf][nf], 0, 0, 0);
        }
    }

    // epilogue
#pragma unroll
    for (int nf = 0; nf < 4; ++nf) {
        const int col = bn + wn + nf * 16 + l16;
        if (col < N) {
            const float bs = bias[col];
#pragma unroll
            for (int mf = 0; mf < 2; ++mf) {
#pragma unroll
                for (int j = 0; j < 4; ++j) {
                    const int row = bm + wm + mf * 16 + l4 * 4 + j;
                    float v = acc[mf][nf][j] + bs;
                    if (ACT == 1) v = 0.5f * v * (1.0f + erff(v * 0.70710678118654752f));
                    if (RES) v += Rr[(size_t)row * N + col];
                    if (OBF) ((unsigned short*)Y)[(size_t)row * N + col] = f2bu(v);
                    else     ((float*)Y)[(size_t)row * N + col] = v;
                }
            }
        }
    }
}

// ---------------------------------------------------------------------------
// Attention (R5, unchanged): per block b; 8 waves = 8 heads
// ---------------------------------------------------------------------------
__global__ __launch_bounds__(512) void attn_kernel(
    const unsigned short* __restrict__ qkv,  // B*6*1632 bf16
    __hip_bfloat16* __restrict__ o)          // B*6*544 bf16
{
    const int b = blockIdx.x;
    __shared__ __align__(16) float sq[KK * 3 * CC];
    __shared__ float sp[HH][40];
    const int tid = threadIdx.x;

    const uint4* src4 = (const uint4*)(qkv + (size_t)b * KK * 3 * CC);  // 1224 uint4
    for (int i = tid; i < (KK * 3 * CC) / 8; i += 512) {
        const uint4 u = src4[i];
        float4 f0, f1;
        f0.x = b2f_lo(u.x); f0.y = b2f_hi(u.x);
        f0.z = b2f_lo(u.y); f0.w = b2f_hi(u.y);
        f1.x = b2f_lo(u.z); f1.y = b2f_hi(u.z);
        f1.z = b2f_lo(u.w); f1.w = b2f_hi(u.w);
        ((float4*)sq)[2 * i] = f0;
        ((float4*)sq)[2 * i + 1] = f1;
    }
    __syncthreads();

    const int h = tid >> 6;
    const int lane = tid & 63;
    const float scl = rsqrtf((float)HD);

    if (lane < KK * KK) {
        const int n = lane / KK, m = lane - (lane / KK) * KK;
        const float* qp = &sq[n * (3 * CC) + 0 * CC + h * HD];
        const float* kp = &sq[m * (3 * CC) + 1 * CC + h * HD];
        float s = 0.0f;
#pragma unroll 4
        for (int d = 0; d < HD; ++d) s += qp[d] * kp[d];
        sp[h][lane] = s * scl;
    }
    __syncthreads();
    if (lane < KK) {
        const int n = lane;
        float mx = -1e30f;
#pragma unroll
        for (int m = 0; m < KK; ++m) mx = fmaxf(mx, sp[h][n * KK + m]);
        float e[KK];
        float sum = 0.0f;
#pragma unroll
        for (int m = 0; m < KK; ++m) { e[m] = expf(sp[h][n * KK + m] - mx); sum += e[m]; }
        const float inv = 1.0f / sum;
#pragma unroll
        for (int m = 0; m < KK; ++m) sp[h][n * KK + m] = e[m] * inv;
    }
    __syncthreads();
    for (int i = tid; i < KK * CC; i += 512) {
        const int n = i / CC;
        const int cd = i - n * CC;
        const int hh = cd / HD;
        const int d = cd - hh * HD;
        float acc = 0.0f;
#pragma unroll
        for (int m = 0; m < KK; ++m)
            acc += sp[hh][n * KK + m] * sq[m * (3 * CC) + 2 * CC + hh * HD + d];
        o[(size_t)b * KK * CC + i] = f2b(acc);
    }
}

// ---------------------------------------------------------------------------
// Final (R5, unchanged): LN(t) with lnf + weighted sum over K
// ---------------------------------------------------------------------------
__global__ __launch_bounds__(256) void final_kernel(
    const float* __restrict__ t, const float* __restrict__ g,
    const float* __restrict__ bta, const float* __restrict__ wm2w,
    const float* __restrict__ wm2b, float* __restrict__ out)
{
    const int b = blockIdx.x;
    const int tid = threadIdx.x;
    __shared__ float st[KK][CC];
    __shared__ float sm[KK], si[KK];
    const float* tb = t + (size_t)b * KK * CC;
    for (int i = tid; i < KK * CC; i += 256) st[i / CC][i % CC] = tb[i];
    __syncthreads();
    const int wid = tid >> 6, lane = tid & 63;
    for (int r = wid; r < KK; r += 4) {
        float s = 0.0f, s2 = 0.0f;
        for (int c = lane; c < CC; c += 64) { const float v = st[r][c]; s += v; s2 += v * v; }
#pragma unroll
        for (int off = 32; off; off >>= 1) { s += __shfl_xor(s, off); s2 += __shfl_xor(s2, off); }
        if (lane == 0) {
            const float m = s / (float)CC;
            sm[r] = m;
            si[r] = rsqrtf(s2 / (float)CC - m * m + EPSF);
        }
    }
    __syncthreads();
    const float w0 = wm2w[0], w1 = wm2w[1], w2 = wm2w[2], w3 = wm2w[3], w4 = wm2w[4], w5 = wm2w[5];
    const float wb = wm2b[0];
    for (int c = tid; c < CC; c += 256) {
        const float gg = g[c], bb = bta[c];
        float acc = wb;
        acc += w0 * ((st[0][c] - sm[0]) * si[0] * gg + bb);
        acc += w1 * ((st[1][c] - sm[1]) * si[1] * gg + bb);
        acc += w2 * ((st[2][c] - sm[2]) * si[2] * gg + bb);
        acc += w3 * ((st[3][c] - sm[3]) * si[3] * gg + bb);
        acc += w4 * ((st[4][c] - sm[4]) * si[4] * gg + bb);
        acc += w5 * ((st[5][c] - sm[5]) * si[5] * gg + bb);
        out[(size_t)b * CC + c] = acc;
    }
}

// ---------------------------------------------------------------------------
extern "C" void kernel_launch(void* const* d_in, const int* in_sizes, int n_in,
                              void* d_out, int out_size, void* d_ws, size_t ws_size,
                              hipStream_t stream)
{
    const float* x      = (const float*)d_in[0];
    const float* pos    = (const float*)d_in[1];
    const float* fc1_w  = (const float*)d_in[2];
    const float* fc2_w  = (const float*)d_in[3];
    const float* ln1_g  = (const float*)d_in[4];
    const float* ln1_b  = (const float*)d_in[5];
    const float* qkv_w  = (const float*)d_in[6];
    const float* qkv_b  = (const float*)d_in[7];
    const float* proj_w = (const float*)d_in[8];
    const float* proj_b = (const float*)d_in[9];
    const float* ln2_g  = (const float*)d_in[10];
    const float* ln2_b  = (const float*)d_in[11];
    const float* mfc1_w = (const float*)d_in[12];
    const float* mfc1_b = (const float*)d_in[13];
    const float* mfc2_w = (const float*)d_in[14];
    const float* mfc2_b = (const float*)d_in[15];
    const float* lnf_g  = (const float*)d_in[16];
    const float* lnf_b  = (const float*)d_in[17];
    const float* wm2_w  = (const float*)d_in[18];
    const float* wm2_b  = (const float*)d_in[19];

    float* ws = (float*)d_ws;
    float* L    = ws;                              // 124416
    float* R    = L + 124416;                      // 124416
    float* pLR  = R + 124416;                      // 486 (+pad)
    float* t    = pLR + 512;                       // 3072*544 f32
    unsigned short* qkvb = (unsigned short*)(t + (size_t)MTOK * CC); // 3072*1632 bf16
    unsigned short* hb  = qkvb + (size_t)MTOK * 3 * CC;              // 3072*544 bf16
    unsigned short* ob  = hb + (size_t)MTOK * CC;                    // 3072*544 bf16
    unsigned short* gb  = ob + (size_t)MTOK * CC;                    // 3072*1088 bf16
    unsigned short* wbf = gb + (size_t)MTOK * HID;                   // 4,734,976 bf16

    unsigned short* wqkv = wbf;                         // 2 x (1632*544)
    unsigned short* wprj = wbf + 1775616;               // 2 x (544*544)
    unsigned short* wf1  = wbf + 2367488;               // 2 x (1088*544)
    unsigned short* wf2  = wbf + 3551232;               // 2 x (544*1088)

    // pure-BW pass: x row half-sums || pos row half-sums || weight conversion
    bw_kernel<<<BW_GRID, 256, 0, stream>>>(
        x, pos, qkv_w, proj_w, mfc1_w, mfc2_w, wbf, L, R, pLR);

    // selection + gather + fused ln1 (layer 0)
    select_kernel<<<BB, 128, 0, stream>>>(
        L, R, pLR, fc1_w, fc2_w, x, pos, ln1_g, ln1_b, t, hb);

    for (int i = 0; i < DEPTH; ++i) {
        if (i > 0) {
            ln_bf16_kernel<<<MTOK / 4, 256, 0, stream>>>(t, ln1_g + i * CC, ln1_b + i * CC, hb);
        }
        gemm_mfma_kernel<0, 0, 1><<<dim3(13, 48), 256, 0, stream>>>(
            hb, wqkv + (size_t)i * 1632 * 544, qkv_b + (size_t)i * 3 * CC,
            nullptr, qkvb, MTOK, 3 * CC, CC);
        attn_kernel<<<BB, 512, 0, stream>>>(qkvb, (__hip_bfloat16*)ob);
        gemm_mfma_kernel<0, 1, 0><<<dim3(5, 48), 256, 0, stream>>>(
            ob, wprj + (size_t)i * 544 * 544, proj_b + (size_t)i * CC,
            t, t, MTOK, CC, CC);
        ln_bf16_kernel<<<MTOK / 4, 256, 0, stream>>>(t, ln2_g + i * CC, ln2_b + i * CC, hb);
        gemm_mfma_kernel<1, 0, 1><<<dim3(9, 48), 256, 0, stream>>>(
            hb, wf1 + (size_t)i * HID * 544, mfc1_b + (size_t)i * HID,
            nullptr, gb, MTOK, HID, CC);
        gemm_mfma_kernel<0, 1, 0><<<dim3(5, 48), 256, 0, stream>>>(
            gb, wf2 + (size_t)i * 544 * HID, mfc2_b + (size_t)i * CC,
            t, t, MTOK, CC, HID);
    }

    final_kernel<<<BB, 256, 0, stream>>>(t, lnf_g, lnf_b, wm2_w, wm2_b, (float*)d_out);
}

// Round 12
// 230.240 us; speedup vs baseline: 1.8584x; 1.0256x over previous
//
#include <hip/hip_runtime.h>
#include <hip/hip_bf16.h>
#include <math.h>

// Problem constants
#define TT 243
#define CC 544            // J*IC
#define NBB 81            // T/BS
#define KK 6
#define HH 8
#define HD 68             // C/H
#define DEPTH 2
#define HID 1088          // 2*C
#define BB 512
#define MTOK 3072         // B*K tokens
#define EPSF 1e-6f

typedef __attribute__((ext_vector_type(8))) short bf16x8;
typedef __attribute__((ext_vector_type(4))) float f32x4;

__device__ __forceinline__ __hip_bfloat16 f2b(float f) { return __float2bfloat16(f); }
__device__ __forceinline__ unsigned short f2bu(float f) {
    __hip_bfloat16 h = __float2bfloat16(f);
    return *(unsigned short*)&h;
}
__device__ __forceinline__ float b2f_lo(unsigned int u) { return __uint_as_float(u << 16); }
__device__ __forceinline__ float b2f_hi(unsigned int u) { return __uint_as_float(u & 0xffff0000u); }

// weight conversion segment ends (float4-index space): qkv | proj | mfc1 | mfc2
#define E0 443904      // 2*1632*544/4
#define E1 591872      // +2*544*544/4
#define E2 887808      // +2*1088*544/4
#define E3 1183744     // +2*544*1088/4

// bw_kernel block ranges
#define RS_BLOCKS 3888            // 3888*32 rows = 124416 = 512*243
#define PS_BLOCKS 8               // 8*32 = 256 >= 243 pos rows
#define WC_BLOCKS 4624            // E3/256
#define BW_GRID (RS_BLOCKS + PS_BLOCKS + WC_BLOCKS)

// ---------------------------------------------------------------------------
// bw_kernel: pure-bandwidth pass (proven R5 version, unchanged)
// ---------------------------------------------------------------------------
__global__ __launch_bounds__(256, 4) void bw_kernel(
    const float* __restrict__ x,     // B*T*C
    const float* __restrict__ pos,   // T*C
    const float* __restrict__ qkvw, const float* __restrict__ projw,
    const float* __restrict__ mfc1w, const float* __restrict__ mfc2w,
    unsigned short* __restrict__ wbf,
    float* __restrict__ L,           // B*T  (x-only)
    float* __restrict__ R,           // B*T  (x-only)
    float* __restrict__ pLR)         // 2*T: pL | pR
{
    const int blk = blockIdx.x;
    const int tid = threadIdx.x;

    if (blk < RS_BLOCKS) {
        const int w = tid >> 6;
        const int lane = tid & 63;
        const int oct = lane & 7;
        const int rsub = lane >> 3;
        const int r = (blk * 4 + w) * 8 + rsub;          // 0..124415
        const float4* xr = (const float4*)x + (size_t)r * 136;
        float4 xs[17];
#pragma unroll
        for (int j = 0; j < 17; ++j) xs[j] = xr[oct + j * 8];
        float aL = 0.0f, aR = 0.0f;
#pragma unroll
        for (int j = 0; j < 17; ++j) {
            const float s = (xs[j].x + xs[j].y) + (xs[j].z + xs[j].w);
            if (j < 8) aL += s;
            else if (j == 8) { if (oct < 4) aL += s; else aR += s; }
            else aR += s;
        }
#pragma unroll
        for (int m = 1; m < 8; m <<= 1) {
            aL += __shfl_xor(aL, m);
            aR += __shfl_xor(aR, m);
        }
        if (oct == 0) { L[r] = aL; R[r] = aR; }
        return;
    }

    if (blk < RS_BLOCKS + PS_BLOCKS) {
        const int w = tid >> 6;
        const int lane = tid & 63;
        const int oct = lane & 7;
        const int rsub = lane >> 3;
        const int r = (blk - RS_BLOCKS) * 32 + w * 8 + rsub;   // 0..255
        const int rc = (r < TT) ? r : (TT - 1);
        const float4* pr = (const float4*)pos + (size_t)rc * 136;
        float4 xs[17];
#pragma unroll
        for (int j = 0; j < 17; ++j) xs[j] = pr[oct + j * 8];
        float aL = 0.0f, aR = 0.0f;
#pragma unroll
        for (int j = 0; j < 17; ++j) {
            const float s = (xs[j].x + xs[j].y) + (xs[j].z + xs[j].w);
            if (j < 8) aL += s;
            else if (j == 8) { if (oct < 4) aL += s; else aR += s; }
            else aR += s;
        }
#pragma unroll
        for (int m = 1; m < 8; m <<= 1) {
            aL += __shfl_xor(aL, m);
            aR += __shfl_xor(aR, m);
        }
        if (oct == 0 && r < TT) { pLR[r] = aL; pLR[TT + r] = aR; }
        return;
    }

    // ---- weight conversion ----
    const int i = (blk - RS_BLOCKS - PS_BLOCKS) * 256 + tid;
    if (i < E3) {
        float4 v;
        if (i < E0)      v = ((const float4*)qkvw)[i];
        else if (i < E1) v = ((const float4*)projw)[i - E0];
        else if (i < E2) v = ((const float4*)mfc1w)[i - E1];
        else             v = ((const float4*)mfc2w)[i - E2];
        ushort4 o;
        o.x = f2bu(v.x); o.y = f2bu(v.y); o.z = f2bu(v.z); o.w = f2bu(v.w);
        ((ushort4*)wbf)[i] = o;
    }
}

// ---------------------------------------------------------------------------
// select: y0, MLP, top-6, gather + fused ln1_0 -> hb (R5, unchanged)
// ---------------------------------------------------------------------------
__global__ __launch_bounds__(128) void select_kernel(
    const float* __restrict__ L, const float* __restrict__ R,
    const float* __restrict__ pLR,
    const float* __restrict__ fc1, const float* __restrict__ fc2,
    const float* __restrict__ x, const float* __restrict__ pos,
    const float* __restrict__ ln1g, const float* __restrict__ ln1b,
    float* __restrict__ t,           // B*6*544 f32
    unsigned short* __restrict__ hb) // B*6*544 bf16 (= ln1_0 output)
{
    const int b = blockIdx.x;
    const int tid = threadIdx.x;
    __shared__ float sf1[NBB * NBB];
    __shared__ float sf2[NBB * NBB];
    __shared__ float sy[NBB], sz[NBB], swv[NBB];
    __shared__ int sidx[KK];
    __shared__ __align__(16) float st[KK][CC];

    const int w = tid >> 6;
    const int lane = tid & 63;
    const float4* x4 = (const float4*)x;
    const float4* p4 = (const float4*)pos;

    for (int i = tid; i < NBB * NBB; i += 128) {
        sf1[i] = fc1[i];
        sf2[i] = fc2[i];
    }

    if (tid < NBB) {
        const int n = tid;
        const float* Lb = L + (size_t)b * TT;
        const float* Rb = R + (size_t)b * TT;
        const float* pL = pLR;
        const float* pR = pLR + TT;
        float s = Lb[3 * n] + Lb[3 * n + 1] + Rb[3 * n] + Rb[3 * n + 1] + Rb[3 * n + 2]
                + pL[3 * n] + pL[3 * n + 1] + pR[3 * n] + pR[3 * n + 1] + pR[3 * n + 2];
        if (n > 0) s += Lb[3 * n - 1] + pL[3 * n - 1];
        sy[n] = s * (1.0f / (3.0f * (float)CC));
    }
    __syncthreads();
    if (tid < NBB) {
        float s = 0.0f;
        for (int j = 0; j < NBB; ++j) s += sf1[tid * NBB + j] * sy[j];
        sz[tid] = fmaxf(s, 0.0f);
    }
    __syncthreads();
    if (tid < NBB) {
        float s = 0.0f;
        for (int j = 0; j < NBB; ++j) s += sf2[tid * NBB + j] * sz[j];
        swv[tid] = 1.0f / (1.0f + expf(-s));
    }
    __syncthreads();
    if (w == 0) {
        float va = (lane < NBB) ? swv[lane] : -1e30f;
        float vb = (lane + 64 < NBB) ? swv[lane + 64] : -1e30f;
        const int ia = lane, ib = lane + 64;
        for (int kk = 0; kk < KK; ++kk) {
            float v = va; int idx = ia;
            if (vb > v) { v = vb; idx = ib; }
#pragma unroll
            for (int m = 1; m < 64; m <<= 1) {
                const float ov = __shfl_xor(v, m);
                const int oi = __shfl_xor(idx, m);
                if (ov > v || (ov == v && oi < idx)) { v = ov; idx = oi; }
            }
            if (lane == 0) sidx[kk] = idx;
            if (ia == idx) va = -1e30f;
            if (ib == idx) vb = -1e30f;
        }
    }
    __syncthreads();

    for (int i = tid; i < KK * 136; i += 128) {
        const int k = i / 136;
        const int c4 = i - k * 136;
        const int n = sidx[k];
        const int shift = (c4 < 68) ? -1 : 0;
        float ax = 0.f, ay = 0.f, az = 0.f, aw = 0.f;
#pragma unroll
        for (int i2 = 0; i2 < 3; ++i2) {
            const int ttr = 3 * n + i2 + shift;
            if (ttr >= 0) {
                const float4 xv = x4[((size_t)b * TT + ttr) * 136 + c4];
                const float4 pv = p4[(size_t)ttr * 136 + c4];
                ax += xv.x + pv.x; ay += xv.y + pv.y; az += xv.z + pv.z; aw += xv.w + pv.w;
            }
        }
        const float inv3 = 1.0f / 3.0f;
        const float4 a = make_float4(ax * inv3, ay * inv3, az * inv3, aw * inv3);
        *(float4*)&st[k][c4 * 4] = a;
        ((float4*)t)[((size_t)b * KK + k) * 136 + c4] = a;
    }
    __syncthreads();

    for (int k = w; k < KK; k += 2) {
        float s = 0.0f, s2 = 0.0f;
        for (int c = lane; c < CC; c += 64) { const float v = st[k][c]; s += v; s2 += v * v; }
#pragma unroll
        for (int off = 32; off; off >>= 1) {
            s += __shfl_xor(s, off);
            s2 += __shfl_xor(s2, off);
        }
        const float m = s / (float)CC;
        const float inv = rsqrtf(s2 / (float)CC - m * m + EPSF);
        for (int c4 = lane; c4 < 136; c4 += 64) {
            const float4 v = *(const float4*)&st[k][c4 * 4];
            const float4 gv = ((const float4*)ln1g)[c4];
            const float4 bv = ((const float4*)ln1b)[c4];
            ushort4 o;
            o.x = f2bu((v.x - m) * inv * gv.x + bv.x);
            o.y = f2bu((v.y - m) * inv * gv.y + bv.y);
            o.z = f2bu((v.z - m) * inv * gv.z + bv.z);
            o.w = f2bu((v.w - m) * inv * gv.w + bv.w);
            ((ushort4*)hb)[((size_t)b * KK + k) * 136 + c4] = o;
        }
    }
}

// ---------------------------------------------------------------------------
// LayerNorm over last dim (544): 4 rows/block, wave per row (R5, unchanged)
// ---------------------------------------------------------------------------
__global__ __launch_bounds__(256) void ln_bf16_kernel(
    const float* __restrict__ X, const float* __restrict__ g,
    const float* __restrict__ bta, unsigned short* __restrict__ Y)
{
    const int row = blockIdx.x * 4 + (threadIdx.x >> 6);
    const int lane = threadIdx.x & 63;
    const float4* xr4 = (const float4*)(X + (size_t)row * CC);
    const float4 v0 = xr4[lane];
    const float4 v1 = xr4[lane + 64];
    float4 v2 = make_float4(0.f, 0.f, 0.f, 0.f);
    if (lane < 8) v2 = xr4[lane + 128];
    float s = (v0.x + v0.y + v0.z + v0.w) + (v1.x + v1.y + v1.z + v1.w)
            + (v2.x + v2.y + v2.z + v2.w);
    float s2 = (v0.x * v0.x + v0.y * v0.y + v0.z * v0.z + v0.w * v0.w)
             + (v1.x * v1.x + v1.y * v1.y + v1.z * v1.z + v1.w * v1.w)
             + (v2.x * v2.x + v2.y * v2.y + v2.z * v2.z + v2.w * v2.w);
#pragma unroll
    for (int off = 32; off; off >>= 1) {
        s += __shfl_xor(s, off);
        s2 += __shfl_xor(s2, off);
    }
    const float m = s / (float)CC;
    const float inv = rsqrtf(s2 / (float)CC - m * m + EPSF);
    ushort4* yr = (ushort4*)(Y + (size_t)row * CC);
    {
        const float4 gv = ((const float4*)g)[lane];
        const float4 bv = ((const float4*)bta)[lane];
        ushort4 o;
        o.x = f2bu((v0.x - m) * inv * gv.x + bv.x);
        o.y = f2bu((v0.y - m) * inv * gv.y + bv.y);
        o.z = f2bu((v0.z - m) * inv * gv.z + bv.z);
        o.w = f2bu((v0.w - m) * inv * gv.w + bv.w);
        yr[lane] = o;
    }
    {
        const float4 gv = ((const float4*)g)[lane + 64];
        const float4 bv = ((const float4*)bta)[lane + 64];
        ushort4 o;
        o.x = f2bu((v1.x - m) * inv * gv.x + bv.x);
        o.y = f2bu((v1.y - m) * inv * gv.y + bv.y);
        o.z = f2bu((v1.z - m) * inv * gv.z + bv.z);
        o.w = f2bu((v1.w - m) * inv * gv.w + bv.w);
        yr[lane + 64] = o;
    }
    if (lane < 8) {
        const float4 gv = ((const float4*)g)[lane + 128];
        const float4 bv = ((const float4*)bta)[lane + 128];
        ushort4 o;
        o.x = f2bu((v2.x - m) * inv * gv.x + bv.x);
        o.y = f2bu((v2.y - m) * inv * gv.y + bv.y);
        o.z = f2bu((v2.z - m) * inv * gv.z + bv.z);
        o.w = f2bu((v2.w - m) * inv * gv.w + bv.w);
        yr[lane + 128] = o;
    }
}

// ---------------------------------------------------------------------------
// bf16 MFMA GEMM, BK=64, 64xBN tile (BN=128 or 64), 4 waves (2x2).
// BN=64 doubles grid parallelism for the narrow N=544 GEMMs (proj/mfc2:
// 240 -> 432 blocks). K-tail zero-padded in LDS (no MFMA guards).
// ---------------------------------------------------------------------------
template <int BN, int ACT, int RES, int OBF>
__global__ __launch_bounds__(256) void gemm_mfma_kernel(
    const unsigned short* __restrict__ X,   // bf16 M x K
    const unsigned short* __restrict__ W,   // bf16 N x K
    const float* __restrict__ bias,         // N
    const float* __restrict__ Rr,           // M x N (f32) or null
    void* __restrict__ Y,                   // f32 or bf16
    int M, int N, int Kd)
{
    constexpr int NF = BN / 32;        // n-frags per wave: 4 (BN=128) / 2 (BN=64)
    const int bm = blockIdx.y * 64;
    const int bn = blockIdx.x * BN;
    const int tid = threadIdx.x;
    const int K8 = Kd >> 3;    // uint4 per row

    __shared__ __align__(16) short As[64][72];
    __shared__ __align__(16) short Bs[BN][72];

    const int r0 = tid >> 2;           // row 0..63
    const int c0 = tid & 3;            // chunk slot 0..3 (of 8 per 64-k step)
    const int r1 = r0 + 64;            // B rows 64..127 (BN=128 only)

    const uint4* Xu = (const uint4*)X;
    const uint4* Wu = (const uint4*)W;

    const int wid = tid >> 6;
    const int lane = tid & 63;
    const int wm = (wid >> 1) * 32;        // 0 or 32
    const int wn = (wid & 1) * (BN / 2);   // 0 or BN/2
    const int l16 = lane & 15;
    const int l4 = lane >> 4;              // 0..3
    const int koff = l4 * 8;

    f32x4 acc[2][NF] = {};

    const int wr0 = min(bn + r0, N - 1);
    const int wr1 = (BN == 128) ? min(bn + r1, N - 1) : 0;

    const uint4 zz = {0u, 0u, 0u, 0u};
    uint4 a00, a01, b00, b01, b10, b11;
    {
        const int k1 = c0, k2 = c0 + 4;
        a00 = (k1 < K8) ? Xu[(size_t)(bm + r0) * K8 + k1] : zz;
        a01 = (k2 < K8) ? Xu[(size_t)(bm + r0) * K8 + k2] : zz;
        b00 = (k1 < K8) ? Wu[(size_t)wr0 * K8 + k1] : zz;
        b01 = (k2 < K8) ? Wu[(size_t)wr0 * K8 + k2] : zz;
        if constexpr (BN == 128) {
            b10 = (c0 < K8) ? Wu[(size_t)wr1 * K8 + c0] : zz;
            b11 = (c0 + 4 < K8) ? Wu[(size_t)wr1 * K8 + c0 + 4] : zz;
        }
    }

    const int nk = (Kd + 63) >> 6;
    for (int kt = 0; kt < nk; ++kt) {
        __syncthreads();
        *(uint4*)&As[r0][c0 * 8]       = a00;
        *(uint4*)&As[r0][(c0 + 4) * 8] = a01;
        *(uint4*)&Bs[r0][c0 * 8]       = b00;
        *(uint4*)&Bs[r0][(c0 + 4) * 8] = b01;
        if constexpr (BN == 128) {
            *(uint4*)&Bs[r1][c0 * 8]       = b10;
            *(uint4*)&Bs[r1][(c0 + 4) * 8] = b11;
        }
        __syncthreads();

        if (kt + 1 < nk) {
            const int k1 = (kt + 1) * 8 + c0;
            const int k2 = k1 + 4;
            a00 = (k1 < K8) ? Xu[(size_t)(bm + r0) * K8 + k1] : zz;
            a01 = (k2 < K8) ? Xu[(size_t)(bm + r0) * K8 + k2] : zz;
            b00 = (k1 < K8) ? Wu[(size_t)wr0 * K8 + k1] : zz;
            b01 = (k2 < K8) ? Wu[(size_t)wr0 * K8 + k2] : zz;
            if constexpr (BN == 128) {
                b10 = (k1 < K8) ? Wu[(size_t)wr1 * K8 + k1] : zz;
                b11 = (k2 < K8) ? Wu[(size_t)wr1 * K8 + k2] : zz;
            }
        }

#pragma unroll
        for (int kh = 0; kh < 2; ++kh) {
            bf16x8 af[2], bf[NF];
#pragma unroll
            for (int mf = 0; mf < 2; ++mf)
                af[mf] = *(const bf16x8*)&As[wm + mf * 16 + l16][kh * 32 + koff];
#pragma unroll
            for (int nf = 0; nf < NF; ++nf)
                bf[nf] = *(const bf16x8*)&Bs[wn + nf * 16 + l16][kh * 32 + koff];
#pragma unroll
            for (int mf = 0; mf < 2; ++mf)
#pragma unroll
                for (int nf = 0; nf < NF; ++nf)
                    acc[mf][nf] = __builtin_amdgcn_mfma_f32_16x16x32_bf16(af[mf], bf[nf], acc[mf][nf], 0, 0, 0);
        }
    }

    // epilogue
#pragma unroll
    for (int nf = 0; nf < NF; ++nf) {
        const int col = bn + wn + nf * 16 + l16;
        if (col < N) {
            const float bs = bias[col];
#pragma unroll
            for (int mf = 0; mf < 2; ++mf) {
#pragma unroll
                for (int j = 0; j < 4; ++j) {
                    const int row = bm + wm + mf * 16 + l4 * 4 + j;
                    float v = acc[mf][nf][j] + bs;
                    if (ACT == 1) v = 0.5f * v * (1.0f + erff(v * 0.70710678118654752f));
                    if (RES) v += Rr[(size_t)row * N + col];
                    if (OBF) ((unsigned short*)Y)[(size_t)row * N + col] = f2bu(v);
                    else     ((float*)Y)[(size_t)row * N + col] = v;
                }
            }
        }
    }
}

// ---------------------------------------------------------------------------
// Attention (R5, unchanged): per block b; 8 waves = 8 heads
// ---------------------------------------------------------------------------
__global__ __launch_bounds__(512) void attn_kernel(
    const unsigned short* __restrict__ qkv,  // B*6*1632 bf16
    __hip_bfloat16* __restrict__ o)          // B*6*544 bf16
{
    const int b = blockIdx.x;
    __shared__ __align__(16) float sq[KK * 3 * CC];
    __shared__ float sp[HH][40];
    const int tid = threadIdx.x;

    const uint4* src4 = (const uint4*)(qkv + (size_t)b * KK * 3 * CC);  // 1224 uint4
    for (int i = tid; i < (KK * 3 * CC) / 8; i += 512) {
        const uint4 u = src4[i];
        float4 f0, f1;
        f0.x = b2f_lo(u.x); f0.y = b2f_hi(u.x);
        f0.z = b2f_lo(u.y); f0.w = b2f_hi(u.y);
        f1.x = b2f_lo(u.z); f1.y = b2f_hi(u.z);
        f1.z = b2f_lo(u.w); f1.w = b2f_hi(u.w);
        ((float4*)sq)[2 * i] = f0;
        ((float4*)sq)[2 * i + 1] = f1;
    }
    __syncthreads();

    const int h = tid >> 6;
    const int lane = tid & 63;
    const float scl = rsqrtf((float)HD);

    if (lane < KK * KK) {
        const int n = lane / KK, m = lane - (lane / KK) * KK;
        const float* qp = &sq[n * (3 * CC) + 0 * CC + h * HD];
        const float* kp = &sq[m * (3 * CC) + 1 * CC + h * HD];
        float s = 0.0f;
#pragma unroll 4
        for (int d = 0; d < HD; ++d) s += qp[d] * kp[d];
        sp[h][lane] = s * scl;
    }
    __syncthreads();
    if (lane < KK) {
        const int n = lane;
        float mx = -1e30f;
#pragma unroll
        for (int m = 0; m < KK; ++m) mx = fmaxf(mx, sp[h][n * KK + m]);
        float e[KK];
        float sum = 0.0f;
#pragma unroll
        for (int m = 0; m < KK; ++m) { e[m] = expf(sp[h][n * KK + m] - mx); sum += e[m]; }
        const float inv = 1.0f / sum;
#pragma unroll
        for (int m = 0; m < KK; ++m) sp[h][n * KK + m] = e[m] * inv;
    }
    __syncthreads();
    for (int i = tid; i < KK * CC; i += 512) {
        const int n = i / CC;
        const int cd = i - n * CC;
        const int hh = cd / HD;
        const int d = cd - hh * HD;
        float acc = 0.0f;
#pragma unroll
        for (int m = 0; m < KK; ++m)
            acc += sp[hh][n * KK + m] * sq[m * (3 * CC) + 2 * CC + hh * HD + d];
        o[(size_t)b * KK * CC + i] = f2b(acc);
    }
}

// ---------------------------------------------------------------------------
// Final (R5, unchanged): LN(t) with lnf + weighted sum over K
// ---------------------------------------------------------------------------
__global__ __launch_bounds__(256) void final_kernel(
    const float* __restrict__ t, const float* __restrict__ g,
    const float* __restrict__ bta, const float* __restrict__ wm2w,
    const float* __restrict__ wm2b, float* __restrict__ out)
{
    const int b = blockIdx.x;
    const int tid = threadIdx.x;
    __shared__ float st[KK][CC];
    __shared__ float sm[KK], si[KK];
    const float* tb = t + (size_t)b * KK * CC;
    for (int i = tid; i < KK * CC; i += 256) st[i / CC][i % CC] = tb[i];
    __syncthreads();
    const int wid = tid >> 6, lane = tid & 63;
    for (int r = wid; r < KK; r += 4) {
        float s = 0.0f, s2 = 0.0f;
        for (int c = lane; c < CC; c += 64) { const float v = st[r][c]; s += v; s2 += v * v; }
#pragma unroll
        for (int off = 32; off; off >>= 1) { s += __shfl_xor(s, off); s2 += __shfl_xor(s2, off); }
        if (lane == 0) {
            const float m = s / (float)CC;
            sm[r] = m;
            si[r] = rsqrtf(s2 / (float)CC - m * m + EPSF);
        }
    }
    __syncthreads();
    const float w0 = wm2w[0], w1 = wm2w[1], w2 = wm2w[2], w3 = wm2w[3], w4 = wm2w[4], w5 = wm2w[5];
    const float wb = wm2b[0];
    for (int c = tid; c < CC; c += 256) {
        const float gg = g[c], bb = bta[c];
        float acc = wb;
        acc += w0 * ((st[0][c] - sm[0]) * si[0] * gg + bb);
        acc += w1 * ((st[1][c] - sm[1]) * si[1] * gg + bb);
        acc += w2 * ((st[2][c] - sm[2]) * si[2] * gg + bb);
        acc += w3 * ((st[3][c] - sm[3]) * si[3] * gg + bb);
        acc += w4 * ((st[4][c] - sm[4]) * si[4] * gg + bb);
        acc += w5 * ((st[5][c] - sm[5]) * si[5] * gg + bb);
        out[(size_t)b * CC + c] = acc;
    }
}

// ---------------------------------------------------------------------------
extern "C" void kernel_launch(void* const* d_in, const int* in_sizes, int n_in,
                              void* d_out, int out_size, void* d_ws, size_t ws_size,
                              hipStream_t stream)
{
    const float* x      = (const float*)d_in[0];
    const float* pos    = (const float*)d_in[1];
    const float* fc1_w  = (const float*)d_in[2];
    const float* fc2_w  = (const float*)d_in[3];
    const float* ln1_g  = (const float*)d_in[4];
    const float* ln1_b  = (const float*)d_in[5];
    const float* qkv_w  = (const float*)d_in[6];
    const float* qkv_b  = (const float*)d_in[7];
    const float* proj_w = (const float*)d_in[8];
    const float* proj_b = (const float*)d_in[9];
    const float* ln2_g  = (const float*)d_in[10];
    const float* ln2_b  = (const float*)d_in[11];
    const float* mfc1_w = (const float*)d_in[12];
    const float* mfc1_b = (const float*)d_in[13];
    const float* mfc2_w = (const float*)d_in[14];
    const float* mfc2_b = (const float*)d_in[15];
    const float* lnf_g  = (const float*)d_in[16];
    const float* lnf_b  = (const float*)d_in[17];
    const float* wm2_w  = (const float*)d_in[18];
    const float* wm2_b  = (const float*)d_in[19];

    float* ws = (float*)d_ws;
    float* L    = ws;                              // 124416
    float* R    = L + 124416;                      // 124416
    float* pLR  = R + 124416;                      // 486 (+pad)
    float* t    = pLR + 512;                       // 3072*544 f32
    unsigned short* qkvb = (unsigned short*)(t + (size_t)MTOK * CC); // 3072*1632 bf16
    unsigned short* hb  = qkvb + (size_t)MTOK * 3 * CC;              // 3072*544 bf16
    unsigned short* ob  = hb + (size_t)MTOK * CC;                    // 3072*544 bf16
    unsigned short* gb  = ob + (size_t)MTOK * CC;                    // 3072*1088 bf16
    unsigned short* wbf = gb + (size_t)MTOK * HID;                   // 4,734,976 bf16

    unsigned short* wqkv = wbf;                         // 2 x (1632*544)
    unsigned short* wprj = wbf + 1775616;               // 2 x (544*544)
    unsigned short* wf1  = wbf + 2367488;               // 2 x (1088*544)
    unsigned short* wf2  = wbf + 3551232;               // 2 x (544*1088)

    // pure-BW pass: x row half-sums || pos row half-sums || weight conversion
    bw_kernel<<<BW_GRID, 256, 0, stream>>>(
        x, pos, qkv_w, proj_w, mfc1_w, mfc2_w, wbf, L, R, pLR);

    // selection + gather + fused ln1 (layer 0)
    select_kernel<<<BB, 128, 0, stream>>>(
        L, R, pLR, fc1_w, fc2_w, x, pos, ln1_g, ln1_b, t, hb);

    for (int i = 0; i < DEPTH; ++i) {
        if (i > 0) {
            ln_bf16_kernel<<<MTOK / 4, 256, 0, stream>>>(t, ln1_g + i * CC, ln1_b + i * CC, hb);
        }
        gemm_mfma_kernel<128, 0, 0, 1><<<dim3(13, 48), 256, 0, stream>>>(
            hb, wqkv + (size_t)i * 1632 * 544, qkv_b + (size_t)i * 3 * CC,
            nullptr, qkvb, MTOK, 3 * CC, CC);
        attn_kernel<<<BB, 512, 0, stream>>>(qkvb, (__hip_bfloat16*)ob);
        gemm_mfma_kernel<64, 0, 1, 0><<<dim3(9, 48), 256, 0, stream>>>(
            ob, wprj + (size_t)i * 544 * 544, proj_b + (size_t)i * CC,
            t, t, MTOK, CC, CC);
        ln_bf16_kernel<<<MTOK / 4, 256, 0, stream>>>(t, ln2_g + i * CC, ln2_b + i * CC, hb);
        gemm_mfma_kernel<128, 1, 0, 1><<<dim3(9, 48), 256, 0, stream>>>(
            hb, wf1 + (size_t)i * HID * 544, mfc1_b + (size_t)i * HID,
            nullptr, gb, MTOK, HID, CC);
        gemm_mfma_kernel<64, 0, 1, 0><<<dim3(9, 48), 256, 0, stream>>>(
            gb, wf2 + (size_t)i * 544 * HID, mfc2_b + (size_t)i * CC,
            t, t, MTOK, CC, HID);
    }

    final_kernel<<<BB, 256, 0, stream>>>(t, lnf_g, lnf_b, wm2_w, wm2_b, (float*)d_out);
}